// Round 2
// baseline (3124.469 us; speedup 1.0000x reference)
//
#include <hip/hip_runtime.h>
#include <cstdint>
#include <cstddef>

#define NN 20000
#define NE 640000
#define NF 64
#define HD 256
#define NL 4

typedef __attribute__((ext_vector_type(8))) short short8;
typedef __attribute__((ext_vector_type(4))) float f32x4;

__device__ __forceinline__ float bf2f(unsigned short u){
  union { unsigned int i; float f; } x; x.i = ((unsigned int)u) << 16; return x.f;
}
__device__ __forceinline__ unsigned short f2bf(float f){
  union { float f; unsigned int i; } x; x.f = f;
  unsigned int r = x.i + 0x7FFFu + ((x.i >> 16) & 1u);   // RNE
  return (unsigned short)(r >> 16);
}
__device__ __forceinline__ float silu_f(float v){
  return v * (1.0f / (1.0f + __expf(-v)));
}
__device__ __forceinline__ void async16(const void* g, void* l){
  __builtin_amdgcn_global_load_lds(
      (const __attribute__((address_space(1))) unsigned int*)g,
      (__attribute__((address_space(3))) unsigned int*)l, 16, 0, 0);
}

// ---------------- prep: weight transpose->bf16, h->bf16, radial ----------------
__global__ __launch_bounds__(256) void prep_k(
    const float* __restrict__ h_in, const float* __restrict__ cd,
    const float* __restrict__ w_in, const float* __restrict__ w_out,
    const float* __restrict__ ew1, const float* __restrict__ ew2,
    const float* __restrict__ nw1, const float* __restrict__ nw2,
    unsigned short* __restrict__ w_in_t, unsigned short* __restrict__ w_out_t,
    unsigned short* __restrict__ ew1t, float* __restrict__ w1r,
    unsigned short* __restrict__ ew2t, unsigned short* __restrict__ nw1t,
    unsigned short* __restrict__ nw2t, unsigned short* __restrict__ hb_in,
    float* __restrict__ radial)
{
  const int s = blockIdx.y;
  const int tid = blockIdx.x * 256 + threadIdx.x;
  if (s == 18) {
    if (tid < NN * NF) hb_in[tid] = f2bf(h_in[tid]);
    return;
  }
  if (s == 19) {
    if (tid < NE) {
      float x = cd[tid*3+0], y = cd[tid*3+1], z = cd[tid*3+2];
      radial[tid] = x*x + y*y + z*z;
    }
    return;
  }
  const float* src; unsigned short* dst; int K, N, dstK; float* extra = nullptr;
  if (s == 0)      { src = w_in;  dst = w_in_t;  K = NF;   N = HD; dstK = NF; }
  else if (s == 1) { src = w_out; dst = w_out_t; K = HD;   N = NF; dstK = HD; }
  else if (s < 6)  { int l = s-2;  src = ew1 + (size_t)l*513*HD;  dst = ew1t + (size_t)l*HD*512; K = 513;  N = HD; dstK = 512; extra = w1r + l*HD; }
  else if (s < 10) { int l = s-6;  src = ew2 + (size_t)l*HD*HD;   dst = ew2t + (size_t)l*HD*HD;  K = HD;   N = HD; dstK = HD; }
  else if (s < 14) { int l = s-10; src = nw1 + (size_t)l*2*HD*HD; dst = nw1t + (size_t)l*HD*512; K = 2*HD; N = HD; dstK = 512; }
  else             { int l = s-14; src = nw2 + (size_t)l*HD*HD;   dst = nw2t + (size_t)l*HD*HD;  K = HD;   N = HD; dstK = HD; }
  if (tid >= K * N) return;
  int k = tid / N, n = tid - k * N;
  float v = src[tid];
  if (k >= dstK) { if (extra) extra[n] = v; return; }   // radial row of edge_w1
  dst[(size_t)n * dstK + k] = f2bf(v);
}

// ---------------- CSR build (counting sort of edges by row) ----------------
__global__ __launch_bounds__(256) void hist_k(const int* __restrict__ erow, int* __restrict__ hist){
  int e = blockIdx.x * 256 + threadIdx.x;
  if (e < NE){
    unsigned r = (unsigned)erow[e]; if (r >= NN) r = 0;
    atomicAdd(&hist[r], 1);
  }
}

__global__ __launch_bounds__(256) void scan_k(const int* __restrict__ hist,
                                              int* __restrict__ starts, int* __restrict__ cursor){
  __shared__ int part[256];
  const int t = threadIdx.x;
  const int CH = 79;                 // 256*79 = 20224 >= 20000
  int lo = t * CH, hi = lo + CH; if (hi > NN) hi = NN; if (lo > NN) lo = NN;
  int s = 0;
  for (int i = lo; i < hi; ++i) s += hist[i];
  part[t] = s; __syncthreads();
  for (int off = 1; off < 256; off <<= 1){
    int v = (t >= off) ? part[t - off] : 0;
    __syncthreads();
    part[t] += v;
    __syncthreads();
  }
  int base = (t == 0) ? 0 : part[t - 1];
  for (int i = lo; i < hi; ++i){ starts[i] = base; cursor[i] = base; base += hist[i]; }
  if (t == 255) starts[NN] = part[255];
}

__global__ __launch_bounds__(256) void scatter_k(const int* __restrict__ erow,
                                                 int* __restrict__ cursor, int* __restrict__ sorted){
  int e = blockIdx.x * 256 + threadIdx.x;
  if (e < NE){
    unsigned r = (unsigned)erow[e]; if (r >= NN) r = 0;
    int pos = atomicAdd(&cursor[r], 1);
    sorted[pos] = e;
  }
}

// ---------------- generic 128x128 bf16 MFMA GEMM: out = [silu](A @ Wt^T + bias) ----------------
__global__ __launch_bounds__(256) void gemm_k(
    const unsigned short* __restrict__ Am, const unsigned short* __restrict__ Wt,
    const float* __restrict__ bias,
    unsigned short* __restrict__ outB, float* __restrict__ outF,
    int M, int N, int K, int fuseSilu)
{
  __shared__ __align__(16) unsigned short As[128*32];
  __shared__ __align__(16) unsigned short Bs[128*32];
  const int t = threadIdx.x;
  const int lane = t & 63, wave = t >> 6;
  const int ln15 = lane & 15, q = lane >> 4;
  const int bm = blockIdx.x, bn = blockIdx.y;
  const int wm = wave >> 1, wn = wave & 1;

  f32x4 acc[4][4];
  #pragma unroll
  for (int i = 0; i < 4; ++i)
    #pragma unroll
    for (int j = 0; j < 4; ++j) acc[i][j] = (f32x4){0.f,0.f,0.f,0.f};

  const int sr = t >> 2;
  const int sc = (t & 3) * 8;
  int am0 = bm*128 + sr;      if (am0 > M-1) am0 = M-1;
  int am1 = bm*128 + 64 + sr; if (am1 > M-1) am1 = M-1;
  int an0 = bn*128 + sr;      if (an0 > N-1) an0 = N-1;
  int an1 = bn*128 + 64 + sr; if (an1 > N-1) an1 = N-1;
  const unsigned short* a0 = Am + (size_t)am0 * K + sc;
  const unsigned short* a1 = Am + (size_t)am1 * K + sc;
  const unsigned short* b0 = Wt + (size_t)an0 * K + sc;
  const unsigned short* b1 = Wt + (size_t)an1 * K + sc;

  const int nkt = K >> 5;
  for (int kt = 0; kt < nkt; ++kt) {
    const int k0 = kt * 32;
    async16(a0 + k0, &As[t*8]);
    async16(a1 + k0, &As[2048 + t*8]);
    async16(b0 + k0, &Bs[t*8]);
    async16(b1 + k0, &Bs[2048 + t*8]);
    __syncthreads();
    short8 fa[4], fb[4];
    #pragma unroll
    for (int i = 0; i < 4; ++i)
      fa[i] = *(const short8*)&As[(wm*64 + i*16 + ln15)*32 + q*8];
    #pragma unroll
    for (int j = 0; j < 4; ++j)
      fb[j] = *(const short8*)&Bs[(wn*64 + j*16 + ln15)*32 + q*8];
    #pragma unroll
    for (int i = 0; i < 4; ++i)
      #pragma unroll
      for (int j = 0; j < 4; ++j)
        acc[i][j] = __builtin_amdgcn_mfma_f32_16x16x32_bf16(fa[i], fb[j], acc[i][j], 0, 0, 0);
    __syncthreads();
  }

  #pragma unroll
  for (int i = 0; i < 4; ++i) {
    #pragma unroll
    for (int j = 0; j < 4; ++j) {
      const int n = bn*128 + wn*64 + j*16 + ln15;
      if (n >= N) continue;
      const float bv = bias ? bias[n] : 0.0f;
      #pragma unroll
      for (int r = 0; r < 4; ++r) {
        const int m = bm*128 + wm*64 + i*16 + q*4 + r;
        if (m >= M) continue;
        float v = acc[i][j][r] + bv;
        if (fuseSilu) v = silu_f(v);
        if (outB) outB[(size_t)m * N + n] = f2bf(v);
        else      outF[(size_t)m * N + n] = v;
      }
    }
  }
}

// ---------------- fused edge MLP + aggregation ----------------
// 64 sorted edges per block; m1 lives in LDS; m2 never hits HBM:
// run-compressed fp32 atomicAdd into agg[node][HD]
__global__ __launch_bounds__(256) void edge_k(
    const unsigned short* __restrict__ hb,
    const int* __restrict__ erow, const int* __restrict__ ecol,
    const float* __restrict__ radial, const int* __restrict__ sorted,
    const unsigned short* __restrict__ w1t,  // [256][512]
    const float* __restrict__ b1, const float* __restrict__ w1r,
    const unsigned short* __restrict__ w2t,  // [256][256]
    const float* __restrict__ b2,
    float* __restrict__ agg)                  // [NN][256] fp32, pre-zeroed
{
  __shared__ __align__(16) unsigned short As[64*32];     //  4 KB
  __shared__ __align__(16) unsigned short Bs[256*32];    // 16 KB
  __shared__ __align__(16) unsigned short M1[64*264];    // 33 KB (stride 264: no phase-2 conflicts)
  __shared__ float radS[64];
  __shared__ int   rowS[64];
  const int t = threadIdx.x;
  const int lane = t & 63, wave = t >> 6;
  const int ln15 = lane & 15, q = lane >> 4;
  const int e0 = blockIdx.x * 64;
  const int sr = t >> 2;
  const int sc = (t & 3) * 8;

  const int es = sorted[e0 + sr];
  unsigned nr = (unsigned)erow[es]; if (nr >= NN) nr = 0;
  unsigned nc = (unsigned)ecol[es]; if (nc >= NN) nc = 0;
  const unsigned short* aR = hb + (size_t)nr * HD + sc;
  const unsigned short* aC = hb + (size_t)nc * HD + sc;
  if (t < 64) {
    int e = sorted[e0 + t];
    radS[t] = radial[e];
    unsigned r = (unsigned)erow[e]; if (r >= NN) r = 0;
    rowS[t] = (int)r;
  }

  f32x4 acc[4][4];
  #pragma unroll
  for (int i = 0; i < 4; ++i)
    #pragma unroll
    for (int j = 0; j < 4; ++j) acc[i][j] = (f32x4){0.f,0.f,0.f,0.f};

  // phase 1: K = 512 (h[row] | h[col])
  for (int kt = 0; kt < 16; ++kt) {
    const int k0 = kt * 32;
    const unsigned short* as = (k0 < HD) ? (aR + k0) : (aC + (k0 - HD));
    async16(as, &As[t*8]);
    #pragma unroll
    for (int p = 0; p < 4; ++p)
      async16(w1t + (size_t)(p*64 + sr)*512 + k0 + sc, &Bs[p*2048 + t*8]);
    __syncthreads();
    short8 fa[4], fb[4];
    #pragma unroll
    for (int i = 0; i < 4; ++i) fa[i] = *(const short8*)&As[(i*16 + ln15)*32 + q*8];
    #pragma unroll
    for (int j = 0; j < 4; ++j) fb[j] = *(const short8*)&Bs[(wave*64 + j*16 + ln15)*32 + q*8];
    #pragma unroll
    for (int i = 0; i < 4; ++i)
      #pragma unroll
      for (int j = 0; j < 4; ++j)
        acc[i][j] = __builtin_amdgcn_mfma_f32_16x16x32_bf16(fa[i], fb[j], acc[i][j], 0, 0, 0);
    __syncthreads();
  }

  // epilogue 1: bias + radial rank-1 term + silu -> M1 (bf16, LDS)
  #pragma unroll
  for (int i = 0; i < 4; ++i) {
    #pragma unroll
    for (int j = 0; j < 4; ++j) {
      const int n = wave*64 + j*16 + ln15;
      const float bv = b1[n], wr = w1r[n];
      #pragma unroll
      for (int r = 0; r < 4; ++r) {
        const int m = i*16 + q*4 + r;
        float v = acc[i][j][r] + bv + radS[m] * wr;
        M1[m*264 + n] = f2bf(silu_f(v));
      }
    }
  }
  __syncthreads();

  // phase 2: K = 256 (M1 @ W2)
  f32x4 acc2[4][4];
  #pragma unroll
  for (int i = 0; i < 4; ++i)
    #pragma unroll
    for (int j = 0; j < 4; ++j) acc2[i][j] = (f32x4){0.f,0.f,0.f,0.f};

  for (int kt = 0; kt < 8; ++kt) {
    const int k0 = kt * 32;
    #pragma unroll
    for (int p = 0; p < 4; ++p)
      async16(w2t + (size_t)(p*64 + sr)*HD + k0 + sc, &Bs[p*2048 + t*8]);
    __syncthreads();
    short8 fa[4], fb[4];
    #pragma unroll
    for (int i = 0; i < 4; ++i) fa[i] = *(const short8*)&M1[(i*16 + ln15)*264 + k0 + q*8];
    #pragma unroll
    for (int j = 0; j < 4; ++j) fb[j] = *(const short8*)&Bs[(wave*64 + j*16 + ln15)*32 + q*8];
    #pragma unroll
    for (int i = 0; i < 4; ++i)
      #pragma unroll
      for (int j = 0; j < 4; ++j)
        acc2[i][j] = __builtin_amdgcn_mfma_f32_16x16x32_bf16(fa[i], fb[j], acc2[i][j], 0, 0, 0);
    __syncthreads();
  }

  // epilogue 2: silu -> run-compressed atomicAdd into agg (sorted rows => runs)
  #pragma unroll
  for (int i = 0; i < 4; ++i) {
    #pragma unroll
    for (int j = 0; j < 4; ++j) {
      const int n = wave*64 + j*16 + ln15;
      const float bv = b2[n];
      const int mb = i*16 + q*4;
      int cur = rowS[mb];
      float s = 0.f;
      #pragma unroll
      for (int r = 0; r < 4; ++r) {
        int node = rowS[mb + r];
        float v = silu_f(acc2[i][j][r] + bv);
        if (node != cur) { atomicAdd(&agg[(size_t)cur * HD + n], s); s = 0.f; cur = node; }
        s += v;
      }
      atomicAdd(&agg[(size_t)cur * HD + n], s);
    }
  }
}

// ---------------- concat: xcat = [h | bf16(agg)] ----------------
__global__ __launch_bounds__(256) void concat_k(
    const unsigned short* __restrict__ h, const float* __restrict__ agg,
    unsigned short* __restrict__ xcat)
{
  const int g = blockIdx.x * 256 + threadIdx.x;   // NN*64 threads, 4 cols each
  const int node = g >> 6;
  const int c = (g & 63) * 4;
  if (node >= NN) return;
  *(ushort4*)(xcat + (size_t)node * 2 * HD + c) =
      *(const ushort4*)(h + (size_t)node * HD + c);
  float4 a = *(const float4*)(agg + (size_t)node * HD + c);
  ushort4 o; o.x = f2bf(a.x); o.y = f2bf(a.y); o.z = f2bf(a.z); o.w = f2bf(a.w);
  *(ushort4*)(xcat + (size_t)node * 2 * HD + HD + c) = o;
}

// ---------------- launch ----------------
extern "C" void kernel_launch(void* const* d_in, const int* in_sizes, int n_in,
                              void* d_out, int out_size, void* d_ws, size_t ws_size,
                              hipStream_t stream)
{
  (void)in_sizes; (void)n_in; (void)out_size; (void)ws_size;
  const float* h_in  = (const float*)d_in[0];
  const int*   ei    = (const int*)d_in[1];
  const float* cd    = (const float*)d_in[2];
  const float* w_in  = (const float*)d_in[3];
  const float* b_in  = (const float*)d_in[4];
  const float* w_out = (const float*)d_in[5];
  const float* b_out = (const float*)d_in[6];
  const float* ew1   = (const float*)d_in[7];
  const float* eb1   = (const float*)d_in[8];
  const float* ew2   = (const float*)d_in[9];
  const float* eb2   = (const float*)d_in[10];
  const float* nw1   = (const float*)d_in[11];
  const float* nb1   = (const float*)d_in[12];
  const float* nw2   = (const float*)d_in[13];
  const float* nb2   = (const float*)d_in[14];
  float* out = (float*)d_out;

  char* base = (char*)d_ws;
  size_t off = 0;
  auto WS = [&](size_t bytes) -> char* {
    char* p = base + off;
    off = (off + bytes + 255) & ~(size_t)255;
    return p;
  };
  float*          radial  = (float*)WS((size_t)NE * 4);              //  2.56 MB
  unsigned short* hb_in   = (unsigned short*)WS((size_t)NN * NF * 2);//  2.56 MB
  unsigned short* hcur    = (unsigned short*)WS((size_t)NN * HD * 2);// 10.24 MB
  unsigned short* xcat    = (unsigned short*)WS((size_t)NN * 2 * HD * 2); // 20.48 MB
  float*          aggF    = (float*)WS((size_t)NN * HD * 4);         // 20.48 MB
  unsigned short* x1      = (unsigned short*)aggF;                   // alias: dead when x1 live
  unsigned short* w_in_t  = (unsigned short*)WS((size_t)NF * HD * 2);
  unsigned short* w_out_t = (unsigned short*)WS((size_t)NF * HD * 2);
  unsigned short* ew1t    = (unsigned short*)WS((size_t)NL * HD * 512 * 2);
  float*          w1r     = (float*)WS((size_t)NL * HD * 4);
  unsigned short* ew2t    = (unsigned short*)WS((size_t)NL * HD * HD * 2);
  unsigned short* nw1t    = (unsigned short*)WS((size_t)NL * HD * 512 * 2);
  unsigned short* nw2t    = (unsigned short*)WS((size_t)NL * HD * HD * 2);
  int*            hist    = (int*)WS((size_t)NN * 4);
  int*            starts  = (int*)WS((size_t)(NN + 1) * 4);
  int*            cursor  = (int*)WS((size_t)NN * 4);
  int*            sorted  = (int*)WS((size_t)NE * 4);                //  2.56 MB
  // total ~ 63 MB

  hipMemsetAsync(hist, 0, (size_t)NN * 4, stream);
  prep_k<<<dim3(5000, 20, 1), 256, 0, stream>>>(h_in, cd, w_in, w_out, ew1, ew2, nw1, nw2,
      w_in_t, w_out_t, ew1t, w1r, ew2t, nw1t, nw2t, hb_in, radial);
  hist_k<<<NE / 256, 256, 0, stream>>>(ei, hist);
  scan_k<<<1, 256, 0, stream>>>(hist, starts, cursor);
  scatter_k<<<NE / 256, 256, 0, stream>>>(ei, cursor, sorted);

  // h = h_in @ w_in + b_in
  gemm_k<<<dim3(157, 2), 256, 0, stream>>>(hb_in, w_in_t, b_in, hcur, nullptr, NN, HD, NF, 0);

  for (int l = 0; l < NL; ++l) {
    hipMemsetAsync(aggF, 0, (size_t)NN * HD * 4, stream);
    edge_k<<<NE / 64, 256, 0, stream>>>(hcur, ei, ei + NE, radial, sorted,
        ew1t + (size_t)l * HD * 512, eb1 + l * HD, w1r + l * HD,
        ew2t + (size_t)l * HD * HD, eb2 + l * HD, aggF);
    concat_k<<<NN * 64 / 256, 256, 0, stream>>>(hcur, aggF, xcat);
    gemm_k<<<dim3(157, 2), 256, 0, stream>>>(xcat, nw1t + (size_t)l * HD * 512,
        nb1 + l * HD, x1, nullptr, NN, HD, 2 * HD, 1);
    gemm_k<<<dim3(157, 2), 256, 0, stream>>>(x1, nw2t + (size_t)l * HD * HD,
        nb2 + l * HD, hcur, nullptr, NN, HD, HD, 0);
  }

  // out = h @ w_out + b_out  (fp32 output)
  gemm_k<<<dim3(157, 1), 256, 0, stream>>>(hcur, w_out_t, b_out, nullptr, out, NN, NF, HD, 0);
}